// Round 3
// baseline (496.259 us; speedup 1.0000x reference)
//
#include <hip/hip_runtime.h>
#include <hip/hip_bf16.h>

// ---------------------------------------------------------------------------
// GIN forward, fused pipeline (all fp32):
//   CSR build (dst adjacency) once per call
//   K1: y1 = x @ W1a                              (K=128 GEMM)
//   K2: zin1 = relu(y1 + gather(y1) + b1a)        (agg)
//   K3: y2 = relu(zin1@W1b + b1b) @ W2a           (fused double GEMM, h1 in LDS)
//   K4: zin2 = relu(y2 + gather(y2) + b2a)        (agg)
//   K5: rowdot = relu(zin2@W2b + b2b) . fcW       -> atomicAdd per graph
//   K6: out[g] = acc[g]/cnt[g] + fcb
// ---------------------------------------------------------------------------

#define NODES 200000
#define EDGES 200000
#define GRAPHS 2048
#define NB_SCAN 782   // ceil(NODES/256)

// ---------------- CSR build ----------------
__global__ __launch_bounds__(256) void count_k(
    const int* __restrict__ ei, int* __restrict__ cnt, int E)
{
    int e = blockIdx.x * 256 + threadIdx.x;
    if (e < E) atomicAdd(&cnt[ei[E + e]], 1);
}

__global__ __launch_bounds__(256) void scan1_k(
    const int* __restrict__ cnt, int* __restrict__ excl,
    int* __restrict__ bsum, int N)
{
    __shared__ int sh[256];
    int tid = threadIdx.x;
    int i = blockIdx.x * 256 + tid;
    int v = (i < N) ? cnt[i] : 0;
    sh[tid] = v;
    __syncthreads();
    for (int off = 1; off < 256; off <<= 1) {
        int t = (tid >= off) ? sh[tid - off] : 0;
        __syncthreads();
        sh[tid] += t;
        __syncthreads();
    }
    if (i < N) excl[i] = sh[tid] - v;
    if (tid == 255) bsum[blockIdx.x] = sh[255];
}

__global__ __launch_bounds__(1024) void scan2_k(int* __restrict__ bsum, int NB)
{
    __shared__ int sh[1024];
    int tid = threadIdx.x;
    int v = (tid < NB) ? bsum[tid] : 0;
    sh[tid] = v;
    __syncthreads();
    for (int off = 1; off < 1024; off <<= 1) {
        int t = (tid >= off) ? sh[tid - off] : 0;
        __syncthreads();
        sh[tid] += t;
        __syncthreads();
    }
    if (tid < NB) bsum[tid] = sh[tid] - v;
}

__global__ __launch_bounds__(256) void scan3_k(
    int* __restrict__ rowptr, const int* __restrict__ bsum,
    int* __restrict__ cursor, int N, int E)
{
    int i = blockIdx.x * 256 + threadIdx.x;
    if (i < N) {
        int v = rowptr[i] + bsum[blockIdx.x];
        rowptr[i] = v;
        cursor[i] = v;
    }
    if (i == 0) rowptr[N] = E;
}

__global__ __launch_bounds__(256) void fill_k(
    const int* __restrict__ ei, int* __restrict__ cursor,
    int* __restrict__ srcs, int E)
{
    int e = blockIdx.x * 256 + threadIdx.x;
    if (e < E) {
        int d = ei[E + e];
        int p = atomicAdd(&cursor[d], 1);
        srcs[p] = ei[e];
    }
}

// ---------------- GEMM core: 64x64 tile, all-float4 LDS reads ----------------
// As: 64 rows, stride 68 floats (float4-aligned pad; bank phase rotates 4/row)
// Ws: 64 rows x 64 cols (for this k-chunk)
__device__ __forceinline__ void gemm_core64(
    const float* __restrict__ As, const float* __restrict__ Ws,
    int ty4, int tx4, float acc[4][4])
{
    #pragma unroll 8
    for (int k4 = 0; k4 < 16; ++k4) {
        const int k = k4 * 4;
        float4 a[4];
        #pragma unroll
        for (int r = 0; r < 4; ++r)
            a[r] = *reinterpret_cast<const float4*>(As + (ty4 + r) * 68 + k);
        #pragma unroll
        for (int j = 0; j < 4; ++j) {
            float4 w = *reinterpret_cast<const float4*>(Ws + (k + j) * 64 + tx4);
            #pragma unroll
            for (int r = 0; r < 4; ++r) {
                const float* ar = reinterpret_cast<const float*>(&a[r]);
                acc[r][0] = fmaf(ar[j], w.x, acc[r][0]);
                acc[r][1] = fmaf(ar[j], w.y, acc[r][1]);
                acc[r][2] = fmaf(ar[j], w.z, acc[r][2]);
                acc[r][3] = fmaf(ar[j], w.w, acc[r][3]);
            }
        }
    }
}

// stage a 64x64 fp32 chunk of A into padded LDS
__device__ __forceinline__ void stage_A64(
    const float* __restrict__ A, int row0, int K, int kc,
    float* __restrict__ As, int tid, float4 v[4])
{
    #pragma unroll
    for (int it = 0; it < 4; ++it) {
        int i = tid + 256 * it;
        int r = i >> 4, c4 = i & 15;
        v[it] = *reinterpret_cast<const float4*>(A + (size_t)(row0 + r) * K + kc + c4 * 4);
    }
}
__device__ __forceinline__ void store_A64(float* __restrict__ As, int tid, const float4 v[4])
{
    #pragma unroll
    for (int it = 0; it < 4; ++it) {
        int i = tid + 256 * it;
        int r = i >> 4, c4 = i & 15;
        *reinterpret_cast<float4*>(As + r * 68 + c4 * 4) = v[it];
    }
}

// ---------------- K1: out = A[N,K] @ W[K,64] ----------------
template<int K>
__global__ __launch_bounds__(256) void gemm_k(
    const float* __restrict__ A, const float* __restrict__ W,
    float* __restrict__ out, int N)
{
    __shared__ float Ws[K * 64];
    __shared__ float As[64 * 68];
    const int tid = threadIdx.x;
    const int row0 = blockIdx.x * 64;

    for (int i = tid; i < K * 16; i += 256)
        reinterpret_cast<float4*>(Ws)[i] = reinterpret_cast<const float4*>(W)[i];

    const int tx4 = (tid & 15) * 4;
    const int ty4 = (tid >> 4) * 4;

    float acc[4][4];
    #pragma unroll
    for (int r = 0; r < 4; ++r)
        #pragma unroll
        for (int c = 0; c < 4; ++c) acc[r][c] = 0.f;

    float4 v[4];
    #pragma unroll
    for (int kc = 0; kc < K; kc += 64) {
        stage_A64(A, row0, K, kc, As, tid, v);
        __syncthreads();
        store_A64(As, tid, v);
        __syncthreads();
        gemm_core64(As, Ws + kc * 64, ty4, tx4, acc);
    }

    #pragma unroll
    for (int r = 0; r < 4; ++r) {
        float4 o = {acc[r][0], acc[r][1], acc[r][2], acc[r][3]};
        *reinterpret_cast<float4*>(out + (size_t)(row0 + ty4 + r) * 64 + tx4) = o;
    }
}

// ---------------- K2/K4: zin[n] = relu(y[n] + sum_{s in N(n)} y[s] + b) ------
__global__ __launch_bounds__(256) void agg_relu_k(
    const float* __restrict__ y, const int* __restrict__ rowptr,
    const int* __restrict__ srcs, const float* __restrict__ bias,
    float* __restrict__ zin, int N)
{
    int t = blockIdx.x * 256 + threadIdx.x;
    int node = t >> 4;
    if (node >= N) return;
    int c = (t & 15) * 4;

    int s0 = rowptr[node];
    int s1 = rowptr[node + 1];

    float4 acc = *reinterpret_cast<const float4*>(y + (size_t)node * 64 + c);
    float4 b4 = *reinterpret_cast<const float4*>(bias + c);
    acc.x += b4.x; acc.y += b4.y; acc.z += b4.z; acc.w += b4.w;

    for (int j = s0; j < s1; ++j) {
        int s = srcs[j];
        float4 vv = *reinterpret_cast<const float4*>(y + (size_t)s * 64 + c);
        acc.x += vv.x; acc.y += vv.y; acc.z += vv.z; acc.w += vv.w;
    }

    float4 o;
    o.x = fmaxf(acc.x, 0.f);
    o.y = fmaxf(acc.y, 0.f);
    o.z = fmaxf(acc.z, 0.f);
    o.w = fmaxf(acc.w, 0.f);
    *reinterpret_cast<float4*>(zin + (size_t)node * 64 + c) = o;
}

// ---------------- K3: out = relu(A@W1 + b1) @ W2 (h1 stays in LDS) ----------
__global__ __launch_bounds__(256) void gemm_gemm_k(
    const float* __restrict__ A, const float* __restrict__ W1,
    const float* __restrict__ bias1, const float* __restrict__ W2,
    float* __restrict__ out, int N)
{
    __shared__ float Ws1[64 * 64];
    __shared__ float Ws2[64 * 64];
    __shared__ float As[64 * 68];
    const int tid = threadIdx.x;
    const int row0 = blockIdx.x * 64;

    for (int i = tid; i < 64 * 16; i += 256) {
        reinterpret_cast<float4*>(Ws1)[i] = reinterpret_cast<const float4*>(W1)[i];
        reinterpret_cast<float4*>(Ws2)[i] = reinterpret_cast<const float4*>(W2)[i];
    }
    float4 v[4];
    stage_A64(A, row0, 64, 0, As, tid, v);

    const int tx4 = (tid & 15) * 4;
    const int ty4 = (tid >> 4) * 4;

    float4 b4 = *reinterpret_cast<const float4*>(bias1 + tx4);
    float acc[4][4];
    #pragma unroll
    for (int r = 0; r < 4; ++r) {
        acc[r][0] = b4.x; acc[r][1] = b4.y; acc[r][2] = b4.z; acc[r][3] = b4.w;
    }

    __syncthreads();   // Ws staged? (grid-stride loop done by all threads) + As not yet stored
    store_A64(As, tid, v);
    __syncthreads();

    gemm_core64(As, Ws1, ty4, tx4, acc);

    __syncthreads();   // all reads of As done; safe to overwrite with h1
    #pragma unroll
    for (int r = 0; r < 4; ++r) {
        float4 o;
        o.x = fmaxf(acc[r][0], 0.f);
        o.y = fmaxf(acc[r][1], 0.f);
        o.z = fmaxf(acc[r][2], 0.f);
        o.w = fmaxf(acc[r][3], 0.f);
        *reinterpret_cast<float4*>(As + (ty4 + r) * 68 + tx4) = o;
        acc[r][0] = 0.f; acc[r][1] = 0.f; acc[r][2] = 0.f; acc[r][3] = 0.f;
    }
    __syncthreads();

    gemm_core64(As, Ws2, ty4, tx4, acc);

    #pragma unroll
    for (int r = 0; r < 4; ++r) {
        float4 o = {acc[r][0], acc[r][1], acc[r][2], acc[r][3]};
        *reinterpret_cast<float4*>(out + (size_t)(row0 + ty4 + r) * 64 + tx4) = o;
    }
}

// ---------------- K5: rowdot = (relu(A@W + b)) . fcW -> atomicAdd per graph --
__global__ __launch_bounds__(256) void gemm_pool_k(
    const float* __restrict__ A, const float* __restrict__ W,
    const float* __restrict__ bias, const float* __restrict__ fcW,
    const int* __restrict__ batch, float* __restrict__ gacc, int N)
{
    __shared__ float Ws[64 * 64];
    __shared__ float As[64 * 68];
    __shared__ float fws[64];
    const int tid = threadIdx.x;
    const int row0 = blockIdx.x * 64;

    for (int i = tid; i < 64 * 16; i += 256)
        reinterpret_cast<float4*>(Ws)[i] = reinterpret_cast<const float4*>(W)[i];
    if (tid < 64) fws[tid] = fcW[tid];

    float4 v[4];
    stage_A64(A, row0, 64, 0, As, tid, v);

    const int tx4 = (tid & 15) * 4;
    const int ty4 = (tid >> 4) * 4;

    float4 b4 = *reinterpret_cast<const float4*>(bias + tx4);
    float acc[4][4];
    #pragma unroll
    for (int r = 0; r < 4; ++r) {
        acc[r][0] = b4.x; acc[r][1] = b4.y; acc[r][2] = b4.z; acc[r][3] = b4.w;
    }

    __syncthreads();
    store_A64(As, tid, v);
    __syncthreads();

    gemm_core64(As, Ws, ty4, tx4, acc);

    // per-thread partial row-dots with fcW, reduce across the 16 col-threads
    float fw0 = fws[tx4], fw1 = fws[tx4 + 1], fw2 = fws[tx4 + 2], fw3 = fws[tx4 + 3];
    #pragma unroll
    for (int r = 0; r < 4; ++r) {
        float dp = fmaxf(acc[r][0], 0.f) * fw0
                 + fmaxf(acc[r][1], 0.f) * fw1
                 + fmaxf(acc[r][2], 0.f) * fw2
                 + fmaxf(acc[r][3], 0.f) * fw3;
        dp += __shfl_down(dp, 8, 16);
        dp += __shfl_down(dp, 4, 16);
        dp += __shfl_down(dp, 2, 16);
        dp += __shfl_down(dp, 1, 16);
        if ((tid & 15) == 0) {
            int row = row0 + ty4 + r;
            atomicAdd(&gacc[batch[row]], dp);
        }
    }
}

// ---------------- K6: out[g] = gacc[g]/cnt[g] + fcb ----------------
__global__ __launch_bounds__(256) void finalize_k(
    const float* __restrict__ gacc, const int* __restrict__ batch,
    const float* __restrict__ fcb, float* __restrict__ out, int N, int G)
{
    int g = blockIdx.x * 256 + threadIdx.x;
    if (g >= G) return;
    int lo = 0, hi = N;
    while (lo < hi) { int m = (lo + hi) >> 1; if (batch[m] < g) lo = m + 1; else hi = m; }
    int start = lo;
    hi = N;
    while (lo < hi) { int m = (lo + hi) >> 1; if (batch[m] < g + 1) lo = m + 1; else hi = m; }
    float cnt = fmaxf((float)(lo - start), 1.f);
    out[g] = gacc[g] / cnt + fcb[0];
}

extern "C" void kernel_launch(void* const* d_in, const int* in_sizes, int n_in,
                              void* d_out, int out_size, void* d_ws, size_t ws_size,
                              hipStream_t stream)
{
    const float* x     = (const float*)d_in[0];
    const int*   ei    = (const int*)d_in[1];   // [2, E] (int32 from harness)
    const int*   batch = (const int*)d_in[2];   // [N], sorted
    const float* W1a   = (const float*)d_in[3];
    const float* b1a   = (const float*)d_in[4];
    const float* W1b   = (const float*)d_in[5];
    const float* b1b   = (const float*)d_in[6];
    const float* W2a   = (const float*)d_in[7];
    const float* b2a   = (const float*)d_in[8];
    const float* W2b   = (const float*)d_in[9];
    const float* b2b   = (const float*)d_in[10];
    const float* fcW   = (const float*)d_in[11];
    const float* fcb   = (const float*)d_in[12];
    float* out = (float*)d_out;

    const int N = NODES, E = EDGES, G = GRAPHS;
    char* ws = (char*)d_ws;
    const size_t szH = (size_t)N * 64 * sizeof(float);   // 51.2 MB

    float* yBuf   = (float*)ws;                 // [0, 51.2)
    float* zinBuf = (float*)(ws + szH);         // [51.2, 102.4)
    char*  rest   = ws + 2 * szH;
    int* cnt    = (int*)rest;           // N
    int* rowptr = cnt + NODES;          // N+1
    int* cursor = rowptr + NODES + 1;   // N
    int* srcs   = cursor + NODES;       // E
    int* bsum   = srcs + EDGES;         // NB_SCAN
    float* gacc = (float*)(bsum + NB_SCAN + 2);

    // ---- CSR build ----
    hipMemsetAsync(cnt, 0, (size_t)N * sizeof(int), stream);
    hipMemsetAsync(gacc, 0, (size_t)G * sizeof(float), stream);
    count_k<<<NB_SCAN, 256, 0, stream>>>(ei, cnt, E);
    scan1_k<<<NB_SCAN, 256, 0, stream>>>(cnt, rowptr, bsum, N);
    scan2_k<<<1, 1024, 0, stream>>>(bsum, NB_SCAN);
    scan3_k<<<NB_SCAN, 256, 0, stream>>>(rowptr, bsum, cursor, N, E);
    fill_k<<<NB_SCAN, 256, 0, stream>>>(ei, cursor, srcs, E);

    // ---- layer 1 ----
    gemm_k<128><<<N / 64, 256, 0, stream>>>(x, W1a, yBuf, N);
    agg_relu_k<<<N * 16 / 256, 256, 0, stream>>>(yBuf, rowptr, srcs, b1a, zinBuf, N);

    // ---- h1 = relu(zin1@W1b+b1b); y2 = h1@W2a  (fused) ----
    gemm_gemm_k<<<N / 64, 256, 0, stream>>>(zinBuf, W1b, b1b, W2a, yBuf, N);

    // ---- layer 2 agg ----
    agg_relu_k<<<N * 16 / 256, 256, 0, stream>>>(yBuf, rowptr, srcs, b2a, zinBuf, N);

    // ---- h2 = relu(zin2@W2b+b2b) fused with pool/fc ----
    gemm_pool_k<<<N / 64, 256, 0, stream>>>(zinBuf, W2b, b2b, fcW, batch, gacc, N);
    finalize_k<<<(G + 255) / 256, 256, 0, stream>>>(gacc, batch, fcb, out, N, G);
}